// Round 2
// baseline (125.660 us; speedup 1.0000x reference)
//
#include <hip/hip_runtime.h>

#define N_FEAT 1024
#define N_LAYER 4

// Algebraic collapse: xi = A_i*x0 + C_i with C_i = sum_{j<i} b_j (row-indep).
//   p_i = <x0, w_i>  (4 independent dots, one reduction phase)
//   e_i = <C_i, w_i> (row-indep; recomputed per wave from L1/L2-cached b,w)
//   s_i = A_i*p_i + e_i ; A_{i+1} = A_i + s_i ; out = A_4*x0 + C_4
// One 64-lane wave per row, 16 elems/lane as 4x float4 (coalesced 16B/lane).
// Single 6-step butterfly reduces all 7 partials with full ILP.
__global__ __launch_bounds__(256) void crossnet_kernel(
    const float* __restrict__ x,
    const float* __restrict__ weight_w,
    const float* __restrict__ weight_b,
    float* __restrict__ out,
    int n_rows) {
  const int wave = threadIdx.x >> 6;
  const int lane = threadIdx.x & 63;
  const int row = blockIdx.x * 4 + wave;
  if (row >= n_rows) return;

  const float4* xrow = (const float4*)(x + (size_t)row * N_FEAT);
  float4* orow = (float4*)(out + (size_t)row * N_FEAT);

  float4 x0[4];     // this row's slice of x, lives in regs
  float4 csum[4];   // C_4 slice = b0+b1+b2+b3
  float p[N_LAYER] = {0.f, 0.f, 0.f, 0.f};  // <x0, w_i> partials
  float e[N_LAYER] = {0.f, 0.f, 0.f, 0.f};  // <C_i, w_i> partials (e[0]=0)

#pragma unroll
  for (int c = 0; c < 4; ++c) {
    x0[c] = xrow[c * 64 + lane];

    float4 w[N_LAYER];
#pragma unroll
    for (int i = 0; i < N_LAYER; ++i)
      w[i] = ((const float4*)(weight_w + i * N_FEAT))[c * 64 + lane];

    // p_i partials on x0 (all independent)
#pragma unroll
    for (int i = 0; i < N_LAYER; ++i) {
      p[i] += x0[c].x * w[i].x + x0[c].y * w[i].y +
              x0[c].z * w[i].z + x0[c].w * w[i].w;
    }

    // cumulative bias + e_i partials: e_i uses C_i = sum_{j<i} b_j
    float4 cum = make_float4(0.f, 0.f, 0.f, 0.f);
#pragma unroll
    for (int i = 0; i < N_LAYER; ++i) {
      if (i > 0) {
        e[i] += cum.x * w[i].x + cum.y * w[i].y +
                cum.z * w[i].z + cum.w * w[i].w;
      }
      float4 b = ((const float4*)(weight_b + i * N_FEAT))[c * 64 + lane];
      cum.x += b.x; cum.y += b.y; cum.z += b.z; cum.w += b.w;
    }
    csum[c] = cum;
  }

  // single butterfly phase: 7 live values, 6 steps, fully interleaved chains
#pragma unroll
  for (int off = 32; off > 0; off >>= 1) {
#pragma unroll
    for (int i = 0; i < N_LAYER; ++i) p[i] += __shfl_xor(p[i], off, 64);
#pragma unroll
    for (int i = 1; i < N_LAYER; ++i) e[i] += __shfl_xor(e[i], off, 64);
  }

  // tiny scalar recurrence (uniform across lanes)
  float A = 1.f;
#pragma unroll
  for (int i = 0; i < N_LAYER; ++i) {
    float s = A * p[i] + e[i];
    A += s;
  }

#pragma unroll
  for (int c = 0; c < 4; ++c) {
    float4 o;
    o.x = fmaf(x0[c].x, A, csum[c].x);
    o.y = fmaf(x0[c].y, A, csum[c].y);
    o.z = fmaf(x0[c].z, A, csum[c].z);
    o.w = fmaf(x0[c].w, A, csum[c].w);
    orow[c * 64 + lane] = o;
  }
}

extern "C" void kernel_launch(void* const* d_in, const int* in_sizes, int n_in,
                              void* d_out, int out_size, void* d_ws, size_t ws_size,
                              hipStream_t stream) {
  const float* x = (const float*)d_in[0];
  const float* ww = (const float*)d_in[1];
  const float* wb = (const float*)d_in[2];
  float* out = (float*)d_out;

  int n_rows = in_sizes[0] / N_FEAT;   // 16384
  int n_blocks = (n_rows + 3) / 4;     // 4 rows (waves) per 256-thread block
  crossnet_kernel<<<n_blocks, 256, 0, stream>>>(x, ww, wb, out, n_rows);
}

// Round 3
// 115.328 us; speedup vs baseline: 1.0896x; 1.0896x over previous
//
#include <hip/hip_runtime.h>

#define N_FEAT 1024
#define N_LAYER 4
#define R 8  // rows per wave: amortizes the 32KB weight+bias reads 8x

// Algebra: xi = A_i*x0 + C_i, C_i = sum_{j<i} b_j (row-independent).
//   p_i = <x0,w_i>  (independent dots), e_i = <C_i,w_i> (row-independent),
//   A_{i+1} = A_i + A_i*p_i + e_i ; out = A_4*x0 + C_4.
// One wave handles R=8 rows: 32 independent float4 HBM loads up front (ILP),
// weights/biases read once per wave instead of once per row. Single butterfly
// reduces all 8*4 p-partials + 3 e-partials with full ILP.
__global__ __launch_bounds__(256) void crossnet_kernel(
    const float* __restrict__ x,
    const float* __restrict__ weight_w,
    const float* __restrict__ weight_b,
    float* __restrict__ out,
    int n_rows) {
  const int wave = threadIdx.x >> 6;
  const int lane = threadIdx.x & 63;
  const int row0 = (blockIdx.x * 4 + wave) * R;
  if (row0 >= n_rows) return;

  const float4* xq = (const float4*)x;   // row stride = 256 float4
  float4* oq = (float4*)out;

  // ---- issue all x loads first: 32 independent 16B/lane HBM loads ----
  float4 x0[R * 4];
#pragma unroll
  for (int r = 0; r < R; ++r)
#pragma unroll
    for (int c = 0; c < 4; ++c)
      x0[r * 4 + c] = xq[(size_t)(row0 + r) * 256 + c * 64 + lane];

  float p[R * N_LAYER];
#pragma unroll
  for (int k = 0; k < R * N_LAYER; ++k) p[k] = 0.f;
  float e[N_LAYER] = {0.f, 0.f, 0.f, 0.f};
  float4 csum[4];

  // ---- per-chunk: load w/b (L1/L2-hot), accumulate partials ----
#pragma unroll
  for (int c = 0; c < 4; ++c) {
    float4 w[N_LAYER];
#pragma unroll
    for (int i = 0; i < N_LAYER; ++i)
      w[i] = ((const float4*)(weight_w + i * N_FEAT))[c * 64 + lane];

    float4 cum = make_float4(0.f, 0.f, 0.f, 0.f);
#pragma unroll
    for (int i = 0; i < N_LAYER; ++i) {
      if (i > 0)
        e[i] += cum.x * w[i].x + cum.y * w[i].y + cum.z * w[i].z + cum.w * w[i].w;
      float4 b = ((const float4*)(weight_b + i * N_FEAT))[c * 64 + lane];
      cum.x += b.x; cum.y += b.y; cum.z += b.z; cum.w += b.w;
    }
    csum[c] = cum;

#pragma unroll
    for (int r = 0; r < R; ++r) {
      const float4 xv = x0[r * 4 + c];
#pragma unroll
      for (int i = 0; i < N_LAYER; ++i) {
        p[r * N_LAYER + i] += xv.x * w[i].x + xv.y * w[i].y +
                              xv.z * w[i].z + xv.w * w[i].w;
      }
    }
  }

  // ---- one butterfly phase: 35 independent values, 6 steps ----
#pragma unroll
  for (int off = 32; off > 0; off >>= 1) {
#pragma unroll
    for (int k = 0; k < R * N_LAYER; ++k) p[k] += __shfl_xor(p[k], off, 64);
#pragma unroll
    for (int i = 1; i < N_LAYER; ++i) e[i] += __shfl_xor(e[i], off, 64);
  }

  // ---- per-row scalar recurrence + streaming store ----
#pragma unroll
  for (int r = 0; r < R; ++r) {
    float A = 1.f;
#pragma unroll
    for (int i = 0; i < N_LAYER; ++i)
      A += A * p[r * N_LAYER + i] + e[i];

#pragma unroll
    for (int c = 0; c < 4; ++c) {
      const float4 xv = x0[r * 4 + c];
      float4 o;
      o.x = fmaf(xv.x, A, csum[c].x);
      o.y = fmaf(xv.y, A, csum[c].y);
      o.z = fmaf(xv.z, A, csum[c].z);
      o.w = fmaf(xv.w, A, csum[c].w);
      oq[(size_t)(row0 + r) * 256 + c * 64 + lane] = o;
    }
  }
}

extern "C" void kernel_launch(void* const* d_in, const int* in_sizes, int n_in,
                              void* d_out, int out_size, void* d_ws, size_t ws_size,
                              hipStream_t stream) {
  const float* x = (const float*)d_in[0];
  const float* ww = (const float*)d_in[1];
  const float* wb = (const float*)d_in[2];
  float* out = (float*)d_out;

  int n_rows = in_sizes[0] / N_FEAT;                 // 16384
  int rows_per_block = 4 * R;                        // 4 waves x 8 rows
  int n_blocks = (n_rows + rows_per_block - 1) / rows_per_block;  // 512
  crossnet_kernel<<<n_blocks, 256, 0, stream>>>(x, ww, wb, out, n_rows);
}